// Round 1
// baseline (590.858 us; speedup 1.0000x reference)
//
#include <hip/hip_runtime.h>

// Problem constants
#define NV   884736      // 96^3 voxels
#define NB   3456        // NV / 256
#define DIM  96
#define DIM2 9216        // 96*96

// 12-byte packed vector (align 4) so gathers are a single dwordx3 load.
struct F3 { float x, y, z; };

__device__ __forceinline__ F3 ld3(const float* f, int idx) {
    return ((const F3*)f)[idx];
}

__device__ __forceinline__ void st3(float* f, int idx, float x, float y, float z) {
    F3 v; v.x = x; v.y = y; v.z = z;
    ((F3*)f)[idx] = v;
}

__device__ __forceinline__ F3 lerp3(F3 a, F3 b, float t, float omt) {
    F3 r;
    r.x = a.x * omt + b.x * t;
    r.y = a.y * omt + b.y * t;
    r.z = a.z * omt + b.z * t;
    return r;
}

// Trilinear sample of an interleaved (float3) 96^3 volume at absolute coords.
// Border semantics EXACTLY as the reference:
//   x0 = clamp((int)floor(x), 0, 95); x1 = min(x0+1, 95); fx = x - floor(x) (unclamped)
__device__ __forceinline__ F3 trisample(const float* f, float x, float y, float z) {
    float xf = floorf(x), yf = floorf(y), zf = floorf(z);
    float fx = x - xf, fy = y - yf, fz = z - zf;
    int x0 = (int)xf; x0 = x0 < 0 ? 0 : (x0 > DIM - 1 ? DIM - 1 : x0);
    int y0 = (int)yf; y0 = y0 < 0 ? 0 : (y0 > DIM - 1 ? DIM - 1 : y0);
    int z0 = (int)zf; z0 = z0 < 0 ? 0 : (z0 > DIM - 1 ? DIM - 1 : z0);
    int x1 = x0 + 1; if (x1 > DIM - 1) x1 = DIM - 1;
    int y1 = y0 + 1; if (y1 > DIM - 1) y1 = DIM - 1;
    int z1 = z0 + 1; if (z1 > DIM - 1) z1 = DIM - 1;
    int X0 = x0 * DIM2, X1 = x1 * DIM2;
    int Y0 = y0 * DIM,  Y1 = y1 * DIM;

    F3 c000 = ld3(f, X0 + Y0 + z0);
    F3 c001 = ld3(f, X0 + Y0 + z1);
    F3 c010 = ld3(f, X0 + Y1 + z0);
    F3 c011 = ld3(f, X0 + Y1 + z1);
    F3 c100 = ld3(f, X1 + Y0 + z0);
    F3 c101 = ld3(f, X1 + Y0 + z1);
    F3 c110 = ld3(f, X1 + Y1 + z0);
    F3 c111 = ld3(f, X1 + Y1 + z1);

    float gz = 1.0f - fz, gy = 1.0f - fy, gx = 1.0f - fx;
    F3 c00 = lerp3(c000, c001, fz, gz);
    F3 c01 = lerp3(c010, c011, fz, gz);
    F3 c10 = lerp3(c100, c101, fz, gz);
    F3 c11 = lerp3(c110, c111, fz, gz);
    F3 c0  = lerp3(c00, c01, fy, gy);
    F3 c1  = lerp3(c10, c11, fy, gy);
    return lerp3(c0, c1, fx, gx);
}

// Init: v0 = +T/128 into fields 0..3, v0 = -T/128 into fields 4..7 (interleaved layout).
// Also zeroes the loss accumulator (d_out is poisoned before every timed launch).
__global__ __launch_bounds__(256) void init_kernel(const float* __restrict__ T,
                                                   float* __restrict__ bufA,
                                                   float* __restrict__ out) {
    int t = blockIdx.y;                       // transform 0..3
    int l = blockIdx.x * 256 + threadIdx.x;   // voxel linear index
    if (t == 0 && l == 0) out[0] = 0.0f;
    const float inv = 1.0f / 128.0f;
    float vx = T[(size_t)(t * 3 + 0) * NV + l] * inv;
    float vy = T[(size_t)(t * 3 + 1) * NV + l] * inv;
    float vz = T[(size_t)(t * 3 + 2) * NV + l] * inv;
    float* pos = bufA + (size_t)t * NV * 3;
    float* neg = bufA + (size_t)(t + 4) * NV * 3;
    st3(pos, l,  vx,  vy,  vz);
    st3(neg, l, -vx, -vy, -vz);
}

// One scaling-and-squaring step for all 8 fields: dst = src + sample(src, grid + src)
__global__ __launch_bounds__(256) void step_kernel(const float* __restrict__ src,
                                                   float* __restrict__ dst) {
    int f = blockIdx.y;                       // field 0..7
    int l = blockIdx.x * 256 + threadIdx.x;
    const float* s = src + (size_t)f * NV * 3;
    float*       d = dst + (size_t)f * NV * 3;
    int k = l % DIM;
    int j = (l / DIM) % DIM;
    int i = l / DIM2;
    F3 v = ld3(s, l);
    F3 smp = trisample(s, (float)i + v.x, (float)j + v.y, (float)k + v.z);
    st3(d, l, v.x + smp.x, v.y + smp.y, v.z + smp.z);
}

// Compose + residual + loss for all 6 pairs, one thread per voxel.
// fields: 0..3 = F_pos, 4..7 = F_neg. loss += sqrt(sum_c (f1 + sample(f2, grid+f1) - R)^2)
__global__ __launch_bounds__(256) void loss_kernel(const float* __restrict__ fields,
                                                   const float* __restrict__ R,
                                                   float* __restrict__ out) {
    int l = blockIdx.x * 256 + threadIdx.x;
    int k = l % DIM;
    int j = (l / DIM) % DIM;
    int i = l / DIM2;
    float fi = (float)i, fj = (float)j, fk = (float)k;

    // F_neg for ref indices 0,1,2 (fields 4,5,6)
    F3 f1c[3];
    #pragma unroll
    for (int r = 0; r < 3; r++)
        f1c[r] = ld3(fields + (size_t)(4 + r) * NV * 3, l);

    // R is (96,96,96,3,6): voxel-major, then channel (x6), then pair. 18 floats/voxel.
    float rbuf[18];
    const float* Rl = R + (size_t)l * 18;
    #pragma unroll
    for (int q = 0; q < 18; q++) rbuf[q] = Rl[q];

    const int REFI[6] = {0, 0, 0, 1, 1, 2};
    const int FLOI[6] = {1, 2, 3, 2, 3, 3};

    float acc = 0.0f;
    #pragma unroll
    for (int p = 0; p < 6; p++) {
        F3 f1 = f1c[REFI[p]];
        const float* f2 = fields + (size_t)FLOI[p] * NV * 3;
        F3 s = trisample(f2, fi + f1.x, fj + f1.y, fk + f1.z);
        float rx = f1.x + s.x - rbuf[0 * 6 + p];
        float ry = f1.y + s.y - rbuf[1 * 6 + p];
        float rz = f1.z + s.z - rbuf[2 * 6 + p];
        acc += sqrtf(rx * rx + ry * ry + rz * rz);
    }

    // Block reduction: wave64 shuffle, then LDS across 4 waves, one atomic per block.
    __shared__ float wsum[4];
    int lane = threadIdx.x & 63;
    int wid  = threadIdx.x >> 6;
    #pragma unroll
    for (int off = 32; off > 0; off >>= 1)
        acc += __shfl_down(acc, off, 64);
    if (lane == 0) wsum[wid] = acc;
    __syncthreads();
    if (threadIdx.x == 0) {
        float s = wsum[0] + wsum[1] + wsum[2] + wsum[3];
        atomicAdd(out, s);
    }
}

extern "C" void kernel_launch(void* const* d_in, const int* in_sizes, int n_in,
                              void* d_out, int out_size, void* d_ws, size_t ws_size,
                              hipStream_t stream) {
    const float* T = (const float*)d_in[0];   // (4,3,96,96,96)
    const float* R = (const float*)d_in[1];   // (96,96,96,3,6)
    float* out = (float*)d_out;               // scalar loss

    // Workspace: two ping-pong buffers of 8 interleaved float3 fields.
    // Each buffer: 8 * 884736 * 3 floats = 84,934,656 B. Total ~162 MB.
    float* bufA = (float*)d_ws;
    float* bufB = bufA + (size_t)8 * NV * 3;

    dim3 blk(256);
    init_kernel<<<dim3(NB, 4), blk, 0, stream>>>(T, bufA, out);

    float* src = bufA;
    float* dst = bufB;
    for (int s = 0; s < 7; s++) {
        step_kernel<<<dim3(NB, 8), blk, 0, stream>>>(src, dst);
        float* tmp = src; src = dst; dst = tmp;
    }
    // After 7 steps, final fields are in `src`.
    loss_kernel<<<NB, blk, 0, stream>>>(src, R, out);
}

// Round 2
// 572.248 us; speedup vs baseline: 1.0325x; 1.0325x over previous
//
#include <hip/hip_runtime.h>

// Problem constants
#define NV    884736     // 96^3 voxels
#define NB    3456       // NV / 256
#define NPAIR 442368     // NV / 2
#define NBP   1728       // NPAIR / 256
#define DIM   96
#define DIM2  9216       // 96*96

// 12-byte packed vector so gathers are a single dwordx3 load.
struct F3 { float x, y, z; };

__device__ __forceinline__ F3 ld3(const float* f, int idx) {
    return ((const F3*)f)[idx];
}

__device__ __forceinline__ void st3(float* f, int idx, float x, float y, float z) {
    F3 v; v.x = x; v.y = y; v.z = z;
    ((F3*)f)[idx] = v;
}

__device__ __forceinline__ F3 lerp3(F3 a, F3 b, float t, float omt) {
    F3 r;
    r.x = a.x * omt + b.x * t;
    r.y = a.y * omt + b.y * t;
    r.z = a.z * omt + b.z * t;
    return r;
}

// Phase-split trilinear sampling: prep (addresses+fracs) / gather / combine.
// Splitting lets the compiler issue ALL gathers of several samples before any
// consumer — maximizes outstanding VMEM per wave (latency hiding).
// Border semantics EXACTLY as reference:
//   x0 = clamp((int)floor(x), 0, 95); x1 = min(x0+1, 95); fx = x - floor(x) (unclamped)
struct TriIdx { int idx[8]; float fx, fy, fz; };

__device__ __forceinline__ TriIdx tri_prep(float x, float y, float z) {
    TriIdx t;
    float xf = floorf(x), yf = floorf(y), zf = floorf(z);
    t.fx = x - xf; t.fy = y - yf; t.fz = z - zf;
    int x0 = (int)xf; x0 = x0 < 0 ? 0 : (x0 > DIM - 1 ? DIM - 1 : x0);
    int y0 = (int)yf; y0 = y0 < 0 ? 0 : (y0 > DIM - 1 ? DIM - 1 : y0);
    int z0 = (int)zf; z0 = z0 < 0 ? 0 : (z0 > DIM - 1 ? DIM - 1 : z0);
    int x1 = x0 + 1; if (x1 > DIM - 1) x1 = DIM - 1;
    int y1 = y0 + 1; if (y1 > DIM - 1) y1 = DIM - 1;
    int z1 = z0 + 1; if (z1 > DIM - 1) z1 = DIM - 1;
    int X0 = x0 * DIM2, X1 = x1 * DIM2;
    int Y0 = y0 * DIM,  Y1 = y1 * DIM;
    t.idx[0] = X0 + Y0 + z0;  t.idx[1] = X0 + Y0 + z1;
    t.idx[2] = X0 + Y1 + z0;  t.idx[3] = X0 + Y1 + z1;
    t.idx[4] = X1 + Y0 + z0;  t.idx[5] = X1 + Y0 + z1;
    t.idx[6] = X1 + Y1 + z0;  t.idx[7] = X1 + Y1 + z1;
    return t;
}

__device__ __forceinline__ void tri_gather(const float* __restrict__ f,
                                           const TriIdx& t, F3 c[8]) {
    #pragma unroll
    for (int q = 0; q < 8; q++) c[q] = ld3(f, t.idx[q]);
}

__device__ __forceinline__ F3 tri_combine(const TriIdx& t, const F3 c[8]) {
    float gz = 1.0f - t.fz, gy = 1.0f - t.fy, gx = 1.0f - t.fx;
    F3 c00 = lerp3(c[0], c[1], t.fz, gz);
    F3 c01 = lerp3(c[2], c[3], t.fz, gz);
    F3 c10 = lerp3(c[4], c[5], t.fz, gz);
    F3 c11 = lerp3(c[6], c[7], t.fz, gz);
    F3 c0  = lerp3(c00, c01, t.fy, gy);
    F3 c1  = lerp3(c10, c11, t.fy, gy);
    return lerp3(c0, c1, t.fx, gx);
}

// Init: v0 = +T/128 into fields 0..3, v0 = -T/128 into fields 4..7.
// Also zeroes the loss accumulator (d_out is poisoned before every timed launch).
__global__ __launch_bounds__(256) void init_kernel(const float* __restrict__ T,
                                                   float* __restrict__ bufA,
                                                   float* __restrict__ out) {
    int t = blockIdx.y;                       // transform 0..3
    int l = blockIdx.x * 256 + threadIdx.x;   // voxel linear index
    if (t == 0 && l == 0) out[0] = 0.0f;
    const float inv = 1.0f / 128.0f;
    float vx = T[(size_t)(t * 3 + 0) * NV + l] * inv;
    float vy = T[(size_t)(t * 3 + 1) * NV + l] * inv;
    float vz = T[(size_t)(t * 3 + 2) * NV + l] * inv;
    float* pos = bufA + (size_t)t * NV * 3;
    float* neg = bufA + (size_t)(t + 4) * NV * 3;
    st3(pos, l,  vx,  vy,  vz);
    st3(neg, l, -vx, -vy, -vz);
}

// One scaling-and-squaring step for all 8 fields: dst = src + sample(src, grid + src).
// 2 voxels per thread (adjacent x-planes) -> 16 gathers in flight per lane.
// Grid is flat; field = blockIdx.x & 7 so that (assuming round-robin block->XCD
// dispatch) each XCD's L2 serves a single field's working set.
__global__ __launch_bounds__(256) void step_kernel(const float* __restrict__ src,
                                                   float* __restrict__ dst) {
    int g = blockIdx.x;
    int f = g & 7;             // field 0..7  (== XCD id under round-robin dispatch)
    int pb = g >> 3;           // pair-block 0..NBP-1
    const float* __restrict__ s = src + (size_t)f * NV * 3;
    float*       __restrict__ d = dst + (size_t)f * NV * 3;

    int l2  = pb * 256 + threadIdx.x;   // 0..NPAIR-1
    int i2  = l2 / DIM2;                // 0..47
    int rem = l2 % DIM2;
    int j   = rem / DIM;
    int k   = rem % DIM;
    int lA  = (2 * i2) * DIM2 + rem;
    int lB  = lA + DIM2;

    F3 vA = ld3(s, lA);
    F3 vB = ld3(s, lB);

    TriIdx tA = tri_prep((float)(2 * i2)     + vA.x, (float)j + vA.y, (float)k + vA.z);
    TriIdx tB = tri_prep((float)(2 * i2 + 1) + vB.x, (float)j + vB.y, (float)k + vB.z);

    F3 cA[8], cB[8];
    tri_gather(s, tA, cA);
    tri_gather(s, tB, cB);

    F3 sA = tri_combine(tA, cA);
    F3 sB = tri_combine(tB, cB);

    st3(d, lA, vA.x + sA.x, vA.y + sA.y, vA.z + sA.z);
    st3(d, lB, vB.x + sB.x, vB.y + sB.y, vB.z + sB.z);
}

// Compose + residual + loss for all 6 pairs, one thread per voxel, samples
// processed two-at-a-time so 16 gathers are in flight per batch.
__global__ __launch_bounds__(256) void loss_kernel(const float* __restrict__ fields,
                                                   const float* __restrict__ R,
                                                   float* __restrict__ out) {
    int l = blockIdx.x * 256 + threadIdx.x;
    int k = l % DIM;
    int j = (l / DIM) % DIM;
    int i = l / DIM2;
    float fi = (float)i, fj = (float)j, fk = (float)k;

    // F_neg for ref indices 0,1,2 (fields 4,5,6)
    F3 f1c[3];
    #pragma unroll
    for (int r = 0; r < 3; r++)
        f1c[r] = ld3(fields + (size_t)(4 + r) * NV * 3, l);

    // R is (96,96,96,3,6): voxel-major, then channel, then pair. 18 floats/voxel.
    float rbuf[18];
    const float* Rl = R + (size_t)l * 18;
    #pragma unroll
    for (int q = 0; q < 18; q++) rbuf[q] = Rl[q];

    const int REFI[6] = {0, 0, 0, 1, 1, 2};
    const int FLOI[6] = {1, 2, 3, 2, 3, 3};

    float acc = 0.0f;
    #pragma unroll
    for (int p = 0; p < 6; p += 2) {
        F3 f1a = f1c[REFI[p]];
        F3 f1b = f1c[REFI[p + 1]];
        const float* __restrict__ f2a = fields + (size_t)FLOI[p]     * NV * 3;
        const float* __restrict__ f2b = fields + (size_t)FLOI[p + 1] * NV * 3;
        TriIdx ta = tri_prep(fi + f1a.x, fj + f1a.y, fk + f1a.z);
        TriIdx tb = tri_prep(fi + f1b.x, fj + f1b.y, fk + f1b.z);
        F3 ca[8], cb[8];
        tri_gather(f2a, ta, ca);
        tri_gather(f2b, tb, cb);
        F3 sa = tri_combine(ta, ca);
        F3 sb = tri_combine(tb, cb);
        float rx = f1a.x + sa.x - rbuf[0 * 6 + p];
        float ry = f1a.y + sa.y - rbuf[1 * 6 + p];
        float rz = f1a.z + sa.z - rbuf[2 * 6 + p];
        acc += sqrtf(rx * rx + ry * ry + rz * rz);
        rx = f1b.x + sb.x - rbuf[0 * 6 + p + 1];
        ry = f1b.y + sb.y - rbuf[1 * 6 + p + 1];
        rz = f1b.z + sb.z - rbuf[2 * 6 + p + 1];
        acc += sqrtf(rx * rx + ry * ry + rz * rz);
    }

    // Block reduction: wave64 shuffle, then LDS across 4 waves, one atomic per block.
    __shared__ float wsum[4];
    int lane = threadIdx.x & 63;
    int wid  = threadIdx.x >> 6;
    #pragma unroll
    for (int off = 32; off > 0; off >>= 1)
        acc += __shfl_down(acc, off, 64);
    if (lane == 0) wsum[wid] = acc;
    __syncthreads();
    if (threadIdx.x == 0) {
        float s = wsum[0] + wsum[1] + wsum[2] + wsum[3];
        atomicAdd(out, s);
    }
}

extern "C" void kernel_launch(void* const* d_in, const int* in_sizes, int n_in,
                              void* d_out, int out_size, void* d_ws, size_t ws_size,
                              hipStream_t stream) {
    const float* T = (const float*)d_in[0];   // (4,3,96,96,96)
    const float* R = (const float*)d_in[1];   // (96,96,96,3,6)
    float* out = (float*)d_out;               // scalar loss

    // Workspace: two ping-pong buffers of 8 interleaved float3 fields (~162 MB).
    float* bufA = (float*)d_ws;
    float* bufB = bufA + (size_t)8 * NV * 3;

    dim3 blk(256);
    init_kernel<<<dim3(NB, 4), blk, 0, stream>>>(T, bufA, out);

    float* src = bufA;
    float* dst = bufB;
    for (int s = 0; s < 7; s++) {
        step_kernel<<<NBP * 8, blk, 0, stream>>>(src, dst);
        float* tmp = src; src = dst; dst = tmp;
    }
    // After 7 steps, final fields are in `src`.
    loss_kernel<<<NB, blk, 0, stream>>>(src, R, out);
}

// Round 3
// 400.144 us; speedup vs baseline: 1.4766x; 1.4301x over previous
//
#include <hip/hip_runtime.h>
#include <hip/hip_fp16.h>

// Problem constants
#define NV    884736     // 96^3 voxels
#define NB    3456       // NV / 256
#define DIM   96
#define DIM2  9216       // 96*96

// Intermediate fields are stored as half4 (x,y,z,pad) = 8 B/voxel.
// A z-adjacent voxel PAIR is 16 contiguous bytes -> one dwordx4 gather
// covers both z-corners of a trilinear cell. 4 gathers/sample, not 8.

union H4 { uint2 u; __half2 h2[2]; };   // one voxel (8 B)
union H8 { uint4 u; __half2 h2[4]; };   // two z-adjacent voxels (16 B)

struct F3 { float x, y, z; };

__device__ __forceinline__ F3 lerp3(F3 a, F3 b, float t, float omt) {
    F3 r;
    r.x = a.x * omt + b.x * t;
    r.y = a.y * omt + b.y * t;
    r.z = a.z * omt + b.z * t;
    return r;
}

__device__ __forceinline__ uint2 pack_h4(float x, float y, float z) {
    H4 v;
    v.h2[0] = __floats2half2_rn(x, y);
    v.h2[1] = __floats2half2_rn(z, 0.0f);
    return v.u;
}

__device__ __forceinline__ F3 unpack_h4(uint2 raw) {
    H4 v; v.u = raw;
    float2 xy = __half22float2(v.h2[0]);
    float2 zp = __half22float2(v.h2[1]);
    F3 r; r.x = xy.x; r.y = xy.y; r.z = zp.x;
    return r;
}

// Phase-split trilinear sampling on half4 fields.
// Border semantics EXACTLY as the reference:
//   x0 = clamp((int)floor(x),0,95); x1 = min(x0+1,95); fx = x - floor(x) (unclamped)
// z edge: when z0==95 we'd need c001==c000; instead force fz=0 so the second
// voxel of the 16B pair (possibly next row / OOB-pad) is multiplied by 0.
struct TriIdx { int idx[4]; float fx, fy, fz; };

__device__ __forceinline__ TriIdx tri_prep(float x, float y, float z) {
    TriIdx t;
    float xf = floorf(x), yf = floorf(y), zf = floorf(z);
    t.fx = x - xf; t.fy = y - yf;
    float fz = z - zf;
    int x0 = (int)xf; x0 = x0 < 0 ? 0 : (x0 > DIM - 1 ? DIM - 1 : x0);
    int y0 = (int)yf; y0 = y0 < 0 ? 0 : (y0 > DIM - 1 ? DIM - 1 : y0);
    int z0 = (int)zf; z0 = z0 < 0 ? 0 : (z0 > DIM - 1 ? DIM - 1 : z0);
    int x1 = x0 + 1; if (x1 > DIM - 1) x1 = DIM - 1;
    int y1 = y0 + 1; if (y1 > DIM - 1) y1 = DIM - 1;
    t.fz = (z0 < DIM - 1) ? fz : 0.0f;
    int X0 = x0 * DIM2, X1 = x1 * DIM2;
    int Y0 = y0 * DIM,  Y1 = y1 * DIM;
    t.idx[0] = X0 + Y0 + z0;   // c00* pair
    t.idx[1] = X0 + Y1 + z0;   // c01* pair
    t.idx[2] = X1 + Y0 + z0;   // c10* pair
    t.idx[3] = X1 + Y1 + z0;   // c11* pair
    return t;
}

__device__ __forceinline__ void tri_gather(const uint2* __restrict__ f,
                                           const TriIdx& t, H8 c[4]) {
    #pragma unroll
    for (int q = 0; q < 4; q++)
        c[q].u = *(const uint4*)(f + t.idx[q]);   // 16B: voxels z0, z0+1
}

__device__ __forceinline__ F3 tri_combine(const TriIdx& t, const H8 c[4]) {
    float gz = 1.0f - t.fz, gy = 1.0f - t.fy, gx = 1.0f - t.fx;
    F3 pz[4];
    #pragma unroll
    for (int q = 0; q < 4; q++) {
        float2 xy0 = __half22float2(c[q].h2[0]);
        float2 z0p = __half22float2(c[q].h2[1]);
        float2 xy1 = __half22float2(c[q].h2[2]);
        float2 z1p = __half22float2(c[q].h2[3]);
        F3 lo; lo.x = xy0.x; lo.y = xy0.y; lo.z = z0p.x;
        F3 hi; hi.x = xy1.x; hi.y = xy1.y; hi.z = z1p.x;
        pz[q] = lerp3(lo, hi, t.fz, gz);
    }
    F3 c0 = lerp3(pz[0], pz[1], t.fy, gy);
    F3 c1 = lerp3(pz[2], pz[3], t.fy, gy);
    return lerp3(c0, c1, t.fx, gx);
}

// Init: v0 = +T/128 into fields 0..3, v0 = -T/128 into fields 4..7 (half4).
// Also zeroes the loss accumulator (d_out is poisoned before every timed launch).
__global__ __launch_bounds__(256) void init_kernel(const float* __restrict__ T,
                                                   uint2* __restrict__ bufA,
                                                   float* __restrict__ out) {
    int t = blockIdx.y;                       // transform 0..3
    int l = blockIdx.x * 256 + threadIdx.x;   // voxel linear index
    if (t == 0 && l == 0) out[0] = 0.0f;
    const float inv = 1.0f / 128.0f;
    float vx = T[(size_t)(t * 3 + 0) * NV + l] * inv;
    float vy = T[(size_t)(t * 3 + 1) * NV + l] * inv;
    float vz = T[(size_t)(t * 3 + 2) * NV + l] * inv;
    bufA[(size_t)t * NV + l]       = pack_h4( vx,  vy,  vz);
    bufA[(size_t)(t + 4) * NV + l] = pack_h4(-vx, -vy, -vz);
}

// One scaling-and-squaring step for all 8 fields: dst = src + sample(src, grid + src).
// field = blockIdx.x & 7 (XCD-affine under round-robin dispatch).
__global__ __launch_bounds__(256) void step_kernel(const uint2* __restrict__ src,
                                                   uint2* __restrict__ dst) {
    int g  = blockIdx.x;
    int f  = g & 7;
    int vb = g >> 3;
    const uint2* __restrict__ s = src + (size_t)f * NV;
    uint2*       __restrict__ d = dst + (size_t)f * NV;

    int l   = vb * 256 + threadIdx.x;
    int i   = l / DIM2;
    int rem = l % DIM2;
    int j   = rem / DIM;
    int k   = rem % DIM;

    F3 v = unpack_h4(s[l]);
    TriIdx t = tri_prep((float)i + v.x, (float)j + v.y, (float)k + v.z);
    H8 c[4];
    tri_gather(s, t, c);
    F3 smp = tri_combine(t, c);
    d[l] = pack_h4(v.x + smp.x, v.y + smp.y, v.z + smp.z);
}

// Compose + residual + loss for all 6 pairs, one thread per voxel,
// two pairs in flight per batch.
__global__ __launch_bounds__(256) void loss_kernel(const uint2* __restrict__ fields,
                                                   const float* __restrict__ R,
                                                   float* __restrict__ out) {
    int l = blockIdx.x * 256 + threadIdx.x;
    int k = l % DIM;
    int j = (l / DIM) % DIM;
    int i = l / DIM2;
    float fi = (float)i, fj = (float)j, fk = (float)k;

    // F_neg for ref indices 0,1,2 (fields 4,5,6)
    F3 f1c[3];
    #pragma unroll
    for (int r = 0; r < 3; r++)
        f1c[r] = unpack_h4(fields[(size_t)(4 + r) * NV + l]);

    // R is (96,96,96,3,6): voxel-major, then channel, then pair. 18 floats/voxel.
    float rbuf[18];
    const float* Rl = R + (size_t)l * 18;
    #pragma unroll
    for (int q = 0; q < 18; q++) rbuf[q] = Rl[q];

    const int REFI[6] = {0, 0, 0, 1, 1, 2};
    const int FLOI[6] = {1, 2, 3, 2, 3, 3};

    float acc = 0.0f;
    #pragma unroll
    for (int p = 0; p < 6; p += 2) {
        F3 f1a = f1c[REFI[p]];
        F3 f1b = f1c[REFI[p + 1]];
        const uint2* __restrict__ f2a = fields + (size_t)FLOI[p]     * NV;
        const uint2* __restrict__ f2b = fields + (size_t)FLOI[p + 1] * NV;
        TriIdx ta = tri_prep(fi + f1a.x, fj + f1a.y, fk + f1a.z);
        TriIdx tb = tri_prep(fi + f1b.x, fj + f1b.y, fk + f1b.z);
        H8 ca[4], cb[4];
        tri_gather(f2a, ta, ca);
        tri_gather(f2b, tb, cb);
        F3 sa = tri_combine(ta, ca);
        F3 sb = tri_combine(tb, cb);
        float rx = f1a.x + sa.x - rbuf[0 * 6 + p];
        float ry = f1a.y + sa.y - rbuf[1 * 6 + p];
        float rz = f1a.z + sa.z - rbuf[2 * 6 + p];
        acc += sqrtf(rx * rx + ry * ry + rz * rz);
        rx = f1b.x + sb.x - rbuf[0 * 6 + p + 1];
        ry = f1b.y + sb.y - rbuf[1 * 6 + p + 1];
        rz = f1b.z + sb.z - rbuf[2 * 6 + p + 1];
        acc += sqrtf(rx * rx + ry * ry + rz * rz);
    }

    // Block reduction: wave64 shuffle, then LDS across 4 waves, one atomic per block.
    __shared__ float wsum[4];
    int lane = threadIdx.x & 63;
    int wid  = threadIdx.x >> 6;
    #pragma unroll
    for (int off = 32; off > 0; off >>= 1)
        acc += __shfl_down(acc, off, 64);
    if (lane == 0) wsum[wid] = acc;
    __syncthreads();
    if (threadIdx.x == 0) {
        float s = wsum[0] + wsum[1] + wsum[2] + wsum[3];
        atomicAdd(out, s);
    }
}

extern "C" void kernel_launch(void* const* d_in, const int* in_sizes, int n_in,
                              void* d_out, int out_size, void* d_ws, size_t ws_size,
                              hipStream_t stream) {
    const float* T = (const float*)d_in[0];   // (4,3,96,96,96) fp32
    const float* R = (const float*)d_in[1];   // (96,96,96,3,6) fp32
    float* out = (float*)d_out;               // scalar loss

    // Workspace: two ping-pong buffers of 8 half4 fields.
    // Each buffer: 8 * 884736 * 8 B = 56.6 MB; +256B slack between/after for
    // the 16B pair-gather that can read 8B past the last voxel.
    uint2* bufA = (uint2*)d_ws;
    uint2* bufB = bufA + (size_t)8 * NV + 32;

    dim3 blk(256);
    init_kernel<<<dim3(NB, 4), blk, 0, stream>>>(T, bufA, out);

    uint2* src = bufA;
    uint2* dst = bufB;
    for (int s = 0; s < 7; s++) {
        step_kernel<<<NB * 8, blk, 0, stream>>>(src, dst);
        uint2* tmp = src; src = dst; dst = tmp;
    }
    // After 7 steps, final fields are in `src`.
    loss_kernel<<<NB, blk, 0, stream>>>(src, R, out);
}